// Round 7
// baseline (976.246 us; speedup 1.0000x reference)
//
#include <hip/hip_runtime.h>
#include <math.h>

#define N_TOK 131072
#define VOCAB 50257
#define DIM   512
#define K_CON 512
#define NPARTS 12565   // ceil(VOCAB/4)

// d_out layout (float32 elements)
#define OFF_ENC  ((size_t)0)
#define OFF_QW   ((size_t)67108864)
#define OFF_DOCU ((size_t)134217728)
#define OFF_OUT  ((size_t)134218240)
#define OFF_VQ   ((size_t)134268497)
#define OFF_LTS  ((size_t)134268498)

// ws layout (bytes)
#define WS_COUNTS 0        // 512 * u32
#define WS_VQ     2048     // double
#define WS_LTS    2056     // double
#define WS_SUMV   2072     // double
#define WS_NFLAG  2080     // u32
#define WS_NARR   4096     // 512 f32
#define WS_SARR   6144     // 512 f32
#define WS_BINC   8192     // VOCAB u32
#define WS_LOGITS 209920   // VOCAB f32 (holds exp(logit))
#define WS_FLAGS  411648   // FLAG_CAP u32
#define WS_PART   444416   // NPARTS double
#define FLAG_CAP  8192

typedef __attribute__((ext_vector_type(4)))  float f32x4;
typedef __attribute__((ext_vector_type(8)))  _Float16 f16x8;
typedef __attribute__((ext_vector_type(16))) float f32x16;

// Codebook as fp16 of (512*c), MFMA fragment layout:
// per step s (16 fp32 dims): [hv 0..1][concept 0..511] x f16x8
//   hv selects dims s*16+hv*8..+7.  Tile = 16 KB; phase = 2 steps = 32 KB.
__device__ _Float16 g_B1[32 * 2 * 512 * 8];   // 512 KB, L2-resident

__device__ inline void gload16(const void* g, void* l) {
    __builtin_amdgcn_global_load_lds(
        (const __attribute__((address_space(1))) unsigned int*)g,
        (__attribute__((address_space(3))) unsigned int*)l, 16, 0, 0);
}

__device__ __forceinline__ f16x8 cvt8(const float4 a0, const float4 a1) {
    f16x8 h;
    h[0] = (_Float16)a0.x; h[1] = (_Float16)a0.y;
    h[2] = (_Float16)a0.z; h[3] = (_Float16)a0.w;
    h[4] = (_Float16)a1.x; h[5] = (_Float16)a1.y;
    h[6] = (_Float16)a1.z; h[7] = (_Float16)a1.w;
    return h;
}

// ---------------------------------------------------------------------------
// merged: n/s arrays + codebook fp16 (512*c) prep
__global__ void k_nsprep(const float* __restrict__ cw, float* __restrict__ n_arr,
                         float* __restrict__ s_arr, _Float16* __restrict__ b1) {
    int w = threadIdx.x >> 6, lane = threadIdx.x & 63;
    int r = blockIdx.x * 4 + w;
    const float* row = cw + (size_t)r * DIM;
    {
        float4 a = *(const float4*)(row + lane * 8);
        float4 b = *(const float4*)(row + lane * 8 + 4);
        float v[8] = {a.x,a.y,a.z,a.w,b.x,b.y,b.z,b.w};
        double na = 0.0, sa = 0.0;
        #pragma unroll
        for (int e = 0; e < 8; ++e) { na += (double)v[e]*v[e]; sa += (double)v[e]; }
        for (int off = 32; off; off >>= 1) {
            na += __shfl_down(na, off);
            sa += __shfl_down(sa, off);
        }
        if (lane == 0) { n_arr[r] = (float)na; s_arr[r] = (float)sa; }
    }
    {
        int s = lane >> 1, hf = lane & 1;
        const float* p = row + s * 16 + hf * 8;
        float4 xa = *(const float4*)p;
        float4 xb = *(const float4*)(p + 4);
        float xf[8] = {xa.x,xa.y,xa.z,xa.w,xb.x,xb.y,xb.z,xb.w};
        f16x8 h8;
        #pragma unroll
        for (int e = 0; e < 8; ++e) h8[e] = (_Float16)(xf[e] * 512.0f);
        *(f16x8*)&b1[(((size_t)s * 2 + hf) * 512 + r) * 8] = h8;
    }
}

// ---------------------------------------------------------------------------
// Main: fp16 single-term MFMA distance GEMM (S = x_h . (512 c)_h; d =
// fmaf(-2^-8, S, nx+nc)). 512 threads = 8 waves (2 token-groups x 4
// concept-quarters). B in 64 KB LDS double-buffer, 16 sync-phases (BK=32).
// Near-tie tokens (gap <= 1e-5) get exact fp32 recompute in k_fixup.
__global__ __launch_bounds__(512, 4)
void k_main(const int* __restrict__ doc, const float* __restrict__ emb,
            const float* __restrict__ cw, const float* __restrict__ n_arr,
            float* __restrict__ out, unsigned* __restrict__ counts,
            unsigned* __restrict__ binc,
            double* __restrict__ vq_acc, unsigned* __restrict__ nflag,
            unsigned* __restrict__ flag_list) {
    __shared__ f16x8 bsh[2][2048];      // 2 x 32 KB double-buffered phase tile
    __shared__ float nsl[512];
    __shared__ float nxs[64];
    __shared__ uint4 redv[8][64];       // 8 KB
    __shared__ int docs[64];
    __shared__ int idxs[64];
    __shared__ double dred[512];        // 4 KB

    const int tid   = threadIdx.x;
    const int n0    = blockIdx.x * 64;
    const int lane  = tid & 63;
    const int wv    = tid >> 6;
    const int wm    = wv >> 2;          // token group 0/1
    const int wq    = wv & 3;           // concept quarter
    const int hv    = lane >> 5;
    const int ln31  = lane & 31;
    const int cbase = wq * 128 + ln31;

    if (tid < 64) docs[tid] = doc[n0 + tid];
    nsl[tid] = n_arr[tid];
    __syncthreads();

#define STAGE_PHASE(P, DST)                                                   \
    {                                                                         \
        const char* srcb = (const char*)g_B1 + (size_t)(P) * 32768;           \
        char* dstb = (char*)(DST);                                            \
        _Pragma("unroll")                                                     \
        for (int i = 0; i < 4; ++i)                                           \
            gload16(srcb + i * 8192 + tid * 16, dstb + i * 8192 + tid * 16);  \
    }

    // stage phase 0 into buf 0 (drained by the pre-pass barrier)
    STAGE_PHASE(0, bsh[0]);

    // nx pre-pass: 8 threads per token, double partials (also warms L2)
    {
        int t = tid >> 3, q = tid & 7;
        const float* xr = emb + (size_t)docs[t] * DIM + q * 64;
        double px = 0.0;
        for (int f = 0; f < 16; ++f) {
            float4 v = *(const float4*)(xr + f * 4);
            px += (double)v.x*v.x + (double)v.y*v.y + (double)v.z*v.z + (double)v.w*v.w;
        }
        dred[tid] = px;
    }

    const float* xrow = emb + (size_t)docs[wm * 32 + ln31] * DIM;
    // prefetch A phase 0: dims {hv*8..+7, 16+hv*8..+7}
    float4 a0 = *(const float4*)(xrow + hv * 8);
    float4 a1 = *(const float4*)(xrow + hv * 8 + 4);
    float4 a2 = *(const float4*)(xrow + 16 + hv * 8);
    float4 a3 = *(const float4*)(xrow + 16 + hv * 8 + 4);

    __syncthreads();   // drains staging 0 + A + nx loads
    if (tid < 64) {
        double s = 0.0;
        #pragma unroll
        for (int q = 0; q < 8; ++q) s += dred[tid * 8 + q];
        nxs[tid] = (float)s;
    }

    f32x16 acc[4];
    #pragma unroll
    for (int n = 0; n < 4; ++n) acc[n] = (f32x16)(0.0f);

    #pragma unroll 2
    for (int p = 0; p < 16; ++p) {
        const int cur = p & 1;
        // issue next-phase staging FIRST: full compute phase to complete
        if (p < 15) STAGE_PHASE(p + 1, bsh[cur ^ 1]);
        // convert prefetched A (both sub-steps)
        f16x8 x0 = cvt8(a0, a1);
        f16x8 x1 = cvt8(a2, a3);
        // prefetch next phase A
        if (p < 15) {
            const float* px = xrow + (p + 1) * 32 + hv * 8;
            a0 = *(const float4*)px;
            a1 = *(const float4*)(px + 4);
            a2 = *(const float4*)(px + 16);
            a3 = *(const float4*)(px + 20);
        }
        // MFMA on current buffer: sub 0 then sub 1
        const f16x8* bb = bsh[cur];
        #pragma unroll
        for (int n = 0; n < 4; ++n) {
            f16x8 b0 = bb[hv * 512 + cbase + n * 32];
            acc[n] = __builtin_amdgcn_mfma_f32_32x32x16_f16(x0, b0, acc[n], 0, 0, 0);
        }
        #pragma unroll
        for (int n = 0; n < 4; ++n) {
            f16x8 b1 = bb[1024 + hv * 512 + cbase + n * 32];
            acc[n] = __builtin_amdgcn_mfma_f32_32x32x16_f16(x1, b1, acc[n], 0, 0, 0);
        }
        __syncthreads();   // drains staging vmcnt; buf cur reads complete
    }
#undef STAGE_PHASE

    float nsv[4];
    #pragma unroll
    for (int n = 0; n < 4; ++n) nsv[n] = nsl[cbase + n * 32];

    // per-row argmin + second best; C/D: col=lane&31, row=(r&3)+8*(r>>2)+4*hv
    // acc holds S = x_h . (512 c)_h ; d = fl(t1 - 2*(S/512)) = fmaf(-2^-8,S,t1)
    #pragma unroll
    for (int r = 0; r < 16; ++r) {
        int tt = (r & 3) + ((r >> 2) << 3) + (hv << 2);   // 0..31 within wm
        float nxr = nxs[wm * 32 + tt];
        float v1 = INFINITY, v2 = INFINITY; int j1 = 0x7fffffff;
        #pragma unroll
        for (int n = 0; n < 4; ++n) {
            float d = fmaf(-0.00390625f, acc[n][r], nxr + nsv[n]);
            int jj = cbase + n * 32;
            if (d < v1) { v2 = v1; v1 = d; j1 = jj; }
            else if (d < v2) { v2 = d; }
        }
        #pragma unroll
        for (int off = 1; off < 32; off <<= 1) {
            float ov1 = __shfl_xor(v1, off);
            int   oj1 = __shfl_xor(j1, off);
            float ov2 = __shfl_xor(v2, off);
            v2 = fminf(fminf(v2, ov2), fmaxf(v1, ov1));
            bool take = (ov1 < v1) || (ov1 == v1 && oj1 < j1);
            if (take) { v1 = ov1; j1 = oj1; }
        }
        if (ln31 == 0)
            redv[wv][wm * 32 + tt] = make_uint4(__float_as_uint(v1), (unsigned)j1,
                                                __float_as_uint(v2), 0u);
    }
    __syncthreads();
    double myv1 = 0.0;
    if (tid < 64) {
        int g = tid >> 5;   // token group
        uint4 a = redv[g * 4][tid];
        float v1 = __uint_as_float(a.x), v2 = __uint_as_float(a.z);
        int j1 = (int)a.y;
        #pragma unroll
        for (int w = 1; w < 4; ++w) {
            uint4 b = redv[g * 4 + w][tid];
            float wv1 = __uint_as_float(b.x), wv2 = __uint_as_float(b.z);
            v2 = fminf(fminf(v2, wv2), fmaxf(v1, wv1));
            bool take = (wv1 < v1) || (wv1 == v1 && (int)b.y < j1);
            if (take) { v1 = wv1; j1 = (int)b.y; }
        }
        idxs[tid] = j1;
        atomicAdd(&counts[j1], 1u);
        atomicAdd(&binc[docs[tid]], 1u);
        myv1 = (double)v1;
        if (v2 - v1 <= 1e-5f) {           // fp16-path tie threshold
            unsigned pq = atomicAdd(nflag, 1u);
            if (pq < FLAG_CAP) flag_list[pq] = (unsigned)(n0 + tid);
        }
    }
    dred[tid] = myv1;
    __syncthreads();

    // encodings: one-hot rows (nontemporal streaming output)
    for (int lin = tid; lin < 8192; lin += 512) {
        int t = lin >> 7, f4 = lin & 127;
        int idx = idxs[t];
        int b4 = f4 << 2;
        f32x4 v;
        v.x = (idx == b4)     ? 1.f : 0.f;
        v.y = (idx == b4 + 1) ? 1.f : 0.f;
        v.z = (idx == b4 + 2) ? 1.f : 0.f;
        v.w = (idx == b4 + 3) ? 1.f : 0.f;
        __builtin_nontemporal_store(v,
            (f32x4*)(out + OFF_ENC + ((size_t)(n0 + t) << 9) + (size_t)b4));
    }
    // quantized_words = codebook rows
    for (int lin = tid; lin < 8192; lin += 512) {
        int t = lin >> 7, f4 = lin & 127;
        f32x4 c4 = *(const f32x4*)(cw + (size_t)idxs[t] * DIM + (f4 << 2));
        __builtin_nontemporal_store(c4,
            (f32x4*)(out + OFF_QW + ((size_t)(n0 + t) << 9) + (size_t)(f4 << 2)));
    }
    // vq partial reduce (provisional: exact v1 patched by fixup for flagged)
    for (int st = 256; st; st >>= 1) {
        if (tid < st) dred[tid] += dred[tid + st];
        __syncthreads();
    }
    if (tid == 0) atomicAdd(vq_acc, dred[0]);
}

// ---------------------------------------------------------------------------
// Exact fp32 recompute for flagged near-tie tokens; patches outputs in place.
__global__ __launch_bounds__(512)
void k_fixup(const int* __restrict__ doc, const float* __restrict__ emb,
             const float* __restrict__ cw, const float* __restrict__ n_arr,
             const unsigned* __restrict__ nflag, const unsigned* __restrict__ flag_list,
             float* __restrict__ out, unsigned* __restrict__ counts,
             double* __restrict__ vq_acc) {
    __shared__ float xs[512];
    __shared__ float nxsh;
    __shared__ int oldj_sh;
    __shared__ float vsh[512];
    __shared__ unsigned long long keys[512];

    const int tid = threadIdx.x;
    unsigned nf = *nflag;
    if (nf > FLAG_CAP) nf = FLAG_CAP;

    for (unsigned f = blockIdx.x; f < nf; f += gridDim.x) {
        int t = (int)flag_list[f];
        int dc = doc[t];
        if (tid < 128)
            *(float4*)&xs[tid * 4] = *(const float4*)(emb + (size_t)dc * DIM + tid * 4);
        if (tid == 0) oldj_sh = -1;
        __syncthreads();
        if (tid == 0) {
            double p[4];
            for (int q = 0; q < 4; ++q) {
                double px = 0.0;
                for (int fq = 0; fq < 32; ++fq) {
                    float4 v = *(const float4*)&xs[q * 128 + fq * 4];
                    px += (double)v.x*v.x + (double)v.y*v.y + (double)v.z*v.z + (double)v.w*v.w;
                }
                p[q] = px;
            }
            nxsh = (float)(((p[0] + p[1]) + p[2]) + p[3]);
        }
        {
            float e = out[OFF_ENC + (size_t)t * 512 + tid];
            if (e == 1.0f) oldj_sh = tid;
        }
        __syncthreads();
        {
            const float* cr = cw + (size_t)tid * DIM;
            float dot = 0.f;
            for (int d = 0; d < 512; ++d) dot = fmaf(xs[d], cr[d], dot);
            float v = fmaf(-2.f, dot, nxsh + n_arr[tid]);
            vsh[tid] = v;
            keys[tid] = (((unsigned long long)__float_as_uint(v)) << 32) | (unsigned)tid;
        }
        __syncthreads();
        for (int st = 256; st; st >>= 1) {
            if (tid < st) {
                unsigned long long o = keys[tid + st];
                if (o < keys[tid]) keys[tid] = o;
            }
            __syncthreads();
        }
        int newj = (int)(keys[0] & 0xffffffffu);
        int oldj = oldj_sh;
        if (newj != oldj) {
            if (tid == 0) {
                out[OFF_ENC + (size_t)t * 512 + oldj] = 0.0f;
                out[OFF_ENC + (size_t)t * 512 + newj] = 1.0f;
                atomicSub(&counts[oldj], 1u);
                atomicAdd(&counts[newj], 1u);
                atomicAdd(vq_acc, (double)vsh[newj] - (double)vsh[oldj]);
            }
            if (tid < 128) {
                float4 cn = *(const float4*)(cw + (size_t)newj * DIM + tid * 4);
                *(float4*)&out[OFF_QW + (size_t)t * 512 + tid * 4] = cn;
            }
        }
        __syncthreads();
    }
}

// ---------------------------------------------------------------------------
__global__ void k_docu(const unsigned* __restrict__ counts,
                       const float* __restrict__ cw, float* __restrict__ out_docu) {
    __shared__ float cnt[512];
    int tid = threadIdx.x;
    cnt[tid] = (float)counts[tid];
    __syncthreads();
    double a = 0.0;
    for (int j = 0; j < K_CON; ++j)
        a += (double)cnt[j] * (double)cw[(size_t)j * DIM + tid];
    out_docu[tid] = (float)(a * (1.0 / (double)N_TOK));
}

__global__ __launch_bounds__(256)
void k_lts(const float* __restrict__ cw, const float* __restrict__ n_arr,
           const float* __restrict__ s_arr, double* __restrict__ lts_acc) {
    __shared__ float ci[4 * 512];
    __shared__ float cjs[64 * 68];
    __shared__ double dred[256];
    const int tid = threadIdx.x;
    const int i0 = blockIdx.x * 4;
    #pragma unroll
    for (int rep = 0; rep < 2; ++rep) {
        int lin = rep * 256 + tid;
        int r = lin >> 7, fq = lin & 127;
        *(float4*)&ci[r*512 + fq*4] = *(const float4*)(cw + (size_t)(i0+r)*DIM + fq*4);
    }
    const int jj = tid & 63, ih = tid >> 6;
    const int ig = i0 + ih;
    const float ni = n_arr[ig], si = s_arr[ig];
    const float EPS = 1e-6f;
    double lsum = 0.0;
    for (int jc = 0; jc < 8; ++jc) {
        float accv = 0.f;
        for (int dc = 0; dc < 8; ++dc) {
            __syncthreads();
            #pragma unroll
            for (int rep = 0; rep < 4; ++rep) {
                int lin = rep * 256 + tid;
                int j = lin >> 4, fq = lin & 15;
                float4 v = *(const float4*)(cw + (size_t)(jc*64 + j)*DIM + dc*64 + fq*4);
                cjs[(fq*4+0)*68 + j] = v.x; cjs[(fq*4+1)*68 + j] = v.y;
                cjs[(fq*4+2)*68 + j] = v.z; cjs[(fq*4+3)*68 + j] = v.w;
            }
            __syncthreads();
            #pragma unroll 4
            for (int d = 0; d < 64; ++d)
                accv = fmaf(ci[ih*512 + dc*64 + d], cjs[d*68 + jj], accv);
        }
        int jg = jc*64 + jj;
        float ddv = ni + n_arr[jg] - 2.f*accv + 2.f*EPS*(si - s_arr[jg]) + 512.f*EPS*EPS;
        float dist = sqrtf(fmaxf(ddv, 0.f));
        lsum += (double)((ig == jg) ? dist : fmaxf(0.f, 1.f - dist));
    }
    dred[tid] = lsum;
    __syncthreads();
    for (int s = 128; s; s >>= 1) {
        if (tid < s) dred[tid] += dred[tid + s];
        __syncthreads();
    }
    if (tid == 0) atomicAdd(lts_acc, dred[0]);
}

// logits -> e = exp(logit + bias), per-block partial sums (no max: |logit| tiny)
__global__ void k_logexp(const float* __restrict__ docu, const float* __restrict__ q2w,
                         const float* __restrict__ q2b, float* __restrict__ evals,
                         double* __restrict__ parts) {
    __shared__ double esh[4];
    int wvi = threadIdx.x >> 6, lane = threadIdx.x & 63;
    int v = blockIdx.x * 4 + wvi;
    if (lane == 0) esh[wvi] = 0.0;
    if (v < VOCAB) {
        const float* wr = q2w + (size_t)v * DIM;
        float4 a = *(const float4*)(wr + lane*8);
        float4 b = *(const float4*)(wr + lane*8 + 4);
        float4 da = *(const float4*)(docu + lane*8);
        float4 db = *(const float4*)(docu + lane*8 + 4);
        float p = a.x*da.x + a.y*da.y + a.z*da.z + a.w*da.w
                + b.x*db.x + b.y*db.y + b.z*db.z + b.w*db.w;
        for (int off = 32; off; off >>= 1) p += __shfl_down(p, off);
        if (lane == 0) {
            float e = expf(p + q2b[v]);
            evals[v] = e;
            esh[wvi] = (double)e;
        }
    }
    __syncthreads();
    if (threadIdx.x == 0)
        parts[blockIdx.x] = esh[0] + esh[1] + esh[2] + esh[3];
}

__global__ void k_sumred(const double* __restrict__ parts, double* __restrict__ sumv) {
    __shared__ double red[256];
    int tid = threadIdx.x;
    double s = 0.0;
    for (int i = tid; i < NPARTS; i += 256) s += parts[i];
    red[tid] = s; __syncthreads();
    for (int st = 128; st; st >>= 1) {
        if (tid < st) red[tid] += red[tid + st];
        __syncthreads();
    }
    if (tid == 0) *sumv = red[0];
}

__global__ void k_final(const float* __restrict__ evals,
                        const double* __restrict__ sumv, const unsigned* __restrict__ binc,
                        const double* __restrict__ vq_acc, const double* __restrict__ lts_acc,
                        float* __restrict__ out) {
    int v = blockIdx.x * 256 + threadIdx.x;
    if (v < VOCAB) {
        float s = (float)(*sumv);
        float p = evals[v] / s;
        out[OFF_OUT + v] = logf(p + 1e-6f) * (float)binc[v];
    }
    if (v == 0) {
        out[OFF_VQ]  = (float)(1.25 * (*vq_acc) * (1.0 / 67108864.0));
        out[OFF_LTS] = (float)((*lts_acc) * (1.0 / 262144.0));
    }
}

// ---------------------------------------------------------------------------
extern "C" void kernel_launch(void* const* d_in, const int* in_sizes, int n_in,
                              void* d_out, int out_size, void* d_ws, size_t ws_size,
                              hipStream_t stream) {
    const int*   doc = (const int*)d_in[0];
    const float* emb = (const float*)d_in[1];
    const float* cw  = (const float*)d_in[2];
    const float* q2w = (const float*)d_in[3];
    const float* q2b = (const float*)d_in[4];
    float* out = (float*)d_out;
    char* ws = (char*)d_ws;

    unsigned* counts = (unsigned*)(ws + WS_COUNTS);
    double*   vq_acc = (double*)(ws + WS_VQ);
    double*   lts_acc= (double*)(ws + WS_LTS);
    double*   sumv   = (double*)(ws + WS_SUMV);
    unsigned* nflag  = (unsigned*)(ws + WS_NFLAG);
    float*    n_arr  = (float*)(ws + WS_NARR);
    float*    s_arr  = (float*)(ws + WS_SARR);
    unsigned* binc   = (unsigned*)(ws + WS_BINC);
    float*    evals  = (float*)(ws + WS_LOGITS);
    unsigned* flags  = (unsigned*)(ws + WS_FLAGS);
    double*   parts  = (double*)(ws + WS_PART);

    _Float16* b1;
    hipGetSymbolAddress((void**)&b1, HIP_SYMBOL(g_B1));

    hipMemsetAsync(ws, 0, 4096, stream);
    hipMemsetAsync(binc, 0, VOCAB * sizeof(unsigned), stream);

    hipLaunchKernelGGL(k_nsprep, dim3(128),  dim3(256), 0, stream, cw, n_arr, s_arr, b1);
    hipLaunchKernelGGL(k_main,   dim3(2048), dim3(512), 0, stream, doc, emb, cw, n_arr,
                       out, counts, binc, vq_acc, nflag, flags);
    hipLaunchKernelGGL(k_fixup,  dim3(256),  dim3(512), 0, stream, doc, emb, cw, n_arr,
                       nflag, flags, out, counts, vq_acc);
    hipLaunchKernelGGL(k_docu,   dim3(1),    dim3(512), 0, stream, counts, cw, out + OFF_DOCU);
    hipLaunchKernelGGL(k_lts,    dim3(128),  dim3(256), 0, stream, cw, n_arr, s_arr, lts_acc);
    hipLaunchKernelGGL(k_logexp, dim3(NPARTS), dim3(256), 0, stream,
                       out + OFF_DOCU, q2w, q2b, evals, parts);
    hipLaunchKernelGGL(k_sumred, dim3(1), dim3(256), 0, stream, parts, sumv);
    hipLaunchKernelGGL(k_final,  dim3((VOCAB + 255) / 256), dim3(256), 0, stream,
                       evals, sumv, binc, vq_acc, lts_acc, out);
}

// Round 8
// 861.973 us; speedup vs baseline: 1.1326x; 1.1326x over previous
//
#include <hip/hip_runtime.h>
#include <math.h>

#define N_TOK 131072
#define VOCAB 50257
#define DIM   512
#define K_CON 512
#define NPARTS 12565   // ceil(VOCAB/4)

// d_out layout (float32 elements)
#define OFF_ENC  ((size_t)0)
#define OFF_QW   ((size_t)67108864)
#define OFF_DOCU ((size_t)134217728)
#define OFF_OUT  ((size_t)134218240)
#define OFF_VQ   ((size_t)134268497)
#define OFF_LTS  ((size_t)134268498)

// ws layout (bytes)
#define WS_COUNTS 0        // 512 * u32
#define WS_VQ     2048     // double
#define WS_LTS    2056     // double
#define WS_SUMV   2072     // double
#define WS_NFLAG  2080     // u32
#define WS_NARR   4096     // 512 f32
#define WS_SARR   6144     // 512 f32
#define WS_BINC   8192     // VOCAB u32
#define WS_LOGITS 209920   // VOCAB f32 (holds exp(logit))
#define WS_FLAGS  411648   // FLAG_CAP u32  (ends 542720)
#define WS_PART   544768   // NPARTS double (ends 645288)
#define FLAG_CAP  32768

typedef __attribute__((ext_vector_type(4)))  float f32x4;
typedef __attribute__((ext_vector_type(8)))  _Float16 f16x8;
typedef __attribute__((ext_vector_type(16))) float f32x16;

// Codebook as fp16 of (512*c), MFMA fragment layout:
// per step s (16 fp32 dims): [hv 0..1][concept 0..511] x f16x8
//   hv selects dims s*16+hv*8..+7.  Phase = 2 steps = 32 KB.
__device__ _Float16 g_B1[32 * 2 * 512 * 8];   // 512 KB, L2-resident

__device__ inline void gload16(const void* g, void* l) {
    __builtin_amdgcn_global_load_lds(
        (const __attribute__((address_space(1))) unsigned int*)g,
        (__attribute__((address_space(3))) unsigned int*)l, 16, 0, 0);
}

__device__ __forceinline__ f16x8 cvt8(const float4 a0, const float4 a1) {
    f16x8 h;
    h[0] = (_Float16)a0.x; h[1] = (_Float16)a0.y;
    h[2] = (_Float16)a0.z; h[3] = (_Float16)a0.w;
    h[4] = (_Float16)a1.x; h[5] = (_Float16)a1.y;
    h[6] = (_Float16)a1.z; h[7] = (_Float16)a1.w;
    return h;
}
__device__ __forceinline__ float sq8(const float4 a0, const float4 a1, float sx) {
    sx = fmaf(a0.x, a0.x, sx); sx = fmaf(a0.y, a0.y, sx);
    sx = fmaf(a0.z, a0.z, sx); sx = fmaf(a0.w, a0.w, sx);
    sx = fmaf(a1.x, a1.x, sx); sx = fmaf(a1.y, a1.y, sx);
    sx = fmaf(a1.z, a1.z, sx); sx = fmaf(a1.w, a1.w, sx);
    return sx;
}

// ---------------------------------------------------------------------------
// merged: n/s arrays + codebook fp16 (512*c) prep
__global__ void k_nsprep(const float* __restrict__ cw, float* __restrict__ n_arr,
                         float* __restrict__ s_arr, _Float16* __restrict__ b1) {
    int w = threadIdx.x >> 6, lane = threadIdx.x & 63;
    int r = blockIdx.x * 4 + w;
    const float* row = cw + (size_t)r * DIM;
    {
        float4 a = *(const float4*)(row + lane * 8);
        float4 b = *(const float4*)(row + lane * 8 + 4);
        float v[8] = {a.x,a.y,a.z,a.w,b.x,b.y,b.z,b.w};
        double na = 0.0, sa = 0.0;
        #pragma unroll
        for (int e = 0; e < 8; ++e) { na += (double)v[e]*v[e]; sa += (double)v[e]; }
        for (int off = 32; off; off >>= 1) {
            na += __shfl_down(na, off);
            sa += __shfl_down(sa, off);
        }
        if (lane == 0) { n_arr[r] = (float)na; s_arr[r] = (float)sa; }
    }
    {
        int s = lane >> 1, hf = lane & 1;
        const float* p = row + s * 16 + hf * 8;
        float4 xa = *(const float4*)p;
        float4 xb = *(const float4*)(p + 4);
        float xf[8] = {xa.x,xa.y,xa.z,xa.w,xb.x,xb.y,xb.z,xb.w};
        f16x8 h8;
        #pragma unroll
        for (int e = 0; e < 8; ++e) h8[e] = (_Float16)(xf[e] * 512.0f);
        *(f16x8*)&b1[(((size_t)s * 2 + hf) * 512 + r) * 8] = h8;
    }
}

// ---------------------------------------------------------------------------
// Main: fp16 single-term MFMA distance GEMM. 512 threads = 8 waves (2
// token-groups x 4 concept-quarters). B in 64 KB LDS dbuf (1 phase ahead),
// A register prefetch 2 phases ahead, nx accumulated in-register from A.
__global__ __launch_bounds__(512, 4)
void k_main(const int* __restrict__ doc, const float* __restrict__ emb,
            const float* __restrict__ cw, const float* __restrict__ n_arr,
            float* __restrict__ out, unsigned* __restrict__ counts,
            unsigned* __restrict__ binc,
            double* __restrict__ vq_acc, unsigned* __restrict__ nflag,
            unsigned* __restrict__ flag_list) {
    __shared__ f16x8 bsh[2][2048];      // 2 x 32 KB double-buffered phase tile
    __shared__ float nsl[512];
    __shared__ float nxs[64];
    __shared__ uint4 redv[8][64];       // 8 KB
    __shared__ int docs[64];
    __shared__ int idxs[64];
    __shared__ double dred[512];        // 4 KB

    const int tid   = threadIdx.x;
    const int n0    = blockIdx.x * 64;
    const int lane  = tid & 63;
    const int wv    = tid >> 6;
    const int wm    = wv >> 2;          // token group 0/1
    const int wq    = wv & 3;           // concept quarter
    const int hv    = lane >> 5;
    const int ln31  = lane & 31;
    const int cbase = wq * 128 + ln31;

    if (tid < 64) docs[tid] = doc[n0 + tid];
    nsl[tid] = n_arr[tid];
    __syncthreads();

#define STAGE_PHASE(P, DST)                                                   \
    {                                                                         \
        const char* srcb = (const char*)g_B1 + (size_t)(P) * 32768;           \
        char* dstb = (char*)(DST);                                            \
        _Pragma("unroll")                                                     \
        for (int i = 0; i < 4; ++i)                                           \
            gload16(srcb + i * 8192 + tid * 16, dstb + i * 8192 + tid * 16);  \
    }

    const float* xrow = emb + (size_t)docs[wm * 32 + ln31] * DIM;

    // prologue: stage B phase 0; prefetch A phases 0 and 1
    STAGE_PHASE(0, bsh[0]);
    float4 aA0 = *(const float4*)(xrow + hv * 8);
    float4 aA1 = *(const float4*)(xrow + hv * 8 + 4);
    float4 aA2 = *(const float4*)(xrow + 16 + hv * 8);
    float4 aA3 = *(const float4*)(xrow + 16 + hv * 8 + 4);
    float4 aB0 = *(const float4*)(xrow + 32 + hv * 8);
    float4 aB1 = *(const float4*)(xrow + 32 + hv * 8 + 4);
    float4 aB2 = *(const float4*)(xrow + 48 + hv * 8);
    float4 aB3 = *(const float4*)(xrow + 48 + hv * 8 + 4);

    __syncthreads();   // drains staging phase 0 + A loads

    f32x16 acc[4];
    #pragma unroll
    for (int n = 0; n < 4; ++n) acc[n] = (f32x16)(0.0f);
    float sx = 0.f;    // this lane's token |x|^2 over its hv-half dims

    #pragma unroll 2
    for (int p = 0; p < 16; ++p) {
        const int cur = p & 1;
        // B staging for phase p+1 FIRST (full compute phase to complete)
        if (p < 15) STAGE_PHASE(p + 1, bsh[cur ^ 1]);
        // use this phase's prefetched A (buffer cur)
        f16x8 x0, x1;
        if (cur == 0) {
            x0 = cvt8(aA0, aA1); x1 = cvt8(aA2, aA3);
            sx = sq8(aA0, aA1, sx); sx = sq8(aA2, aA3, sx);
            if (p < 14) {   // reload this buffer with phase p+2
                const float* px = xrow + (p + 2) * 32 + hv * 8;
                aA0 = *(const float4*)px;        aA1 = *(const float4*)(px + 4);
                aA2 = *(const float4*)(px + 16); aA3 = *(const float4*)(px + 20);
            }
        } else {
            x0 = cvt8(aB0, aB1); x1 = cvt8(aB2, aB3);
            sx = sq8(aB0, aB1, sx); sx = sq8(aB2, aB3, sx);
            if (p < 14) {
                const float* px = xrow + (p + 2) * 32 + hv * 8;
                aB0 = *(const float4*)px;        aB1 = *(const float4*)(px + 4);
                aB2 = *(const float4*)(px + 16); aB3 = *(const float4*)(px + 20);
            }
        }
        // MFMA on current buffer: sub-step 0 then 1
        const f16x8* bb = bsh[cur];
        #pragma unroll
        for (int n = 0; n < 4; ++n) {
            f16x8 b0 = bb[hv * 512 + cbase + n * 32];
            acc[n] = __builtin_amdgcn_mfma_f32_32x32x16_f16(x0, b0, acc[n], 0, 0, 0);
        }
        #pragma unroll
        for (int n = 0; n < 4; ++n) {
            f16x8 b1 = bb[1024 + hv * 512 + cbase + n * 32];
            acc[n] = __builtin_amdgcn_mfma_f32_32x32x16_f16(x1, b1, acc[n], 0, 0, 0);
        }
        __syncthreads();   // drains staging vmcnt; buf cur reads complete
    }
#undef STAGE_PHASE

    // nx per token: combine hv halves; wq==0 waves publish
    {
        float sxt = sx + __shfl_xor(sx, 32);
        if (wq == 0 && hv == 0) nxs[wm * 32 + ln31] = sxt;
    }
    __syncthreads();

    float nsv[4];
    #pragma unroll
    for (int n = 0; n < 4; ++n) nsv[n] = nsl[cbase + n * 32];

    // per-row argmin + second best; C/D: col=lane&31, row=(r&3)+8*(r>>2)+4*hv
    // acc holds S = x_h . (512 c)_h ; d = fmaf(-2^-8, S, nx+nc)
    #pragma unroll
    for (int r = 0; r < 16; ++r) {
        int tt = (r & 3) + ((r >> 2) << 3) + (hv << 2);   // 0..31 within wm
        float nxr = nxs[wm * 32 + tt];
        float v1 = INFINITY, v2 = INFINITY; int j1 = 0x7fffffff;
        #pragma unroll
        for (int n = 0; n < 4; ++n) {
            float d = fmaf(-0.00390625f, acc[n][r], nxr + nsv[n]);
            int jj = cbase + n * 32;
            if (d < v1) { v2 = v1; v1 = d; j1 = jj; }
            else if (d < v2) { v2 = d; }
        }
        #pragma unroll
        for (int off = 1; off < 32; off <<= 1) {
            float ov1 = __shfl_xor(v1, off);
            int   oj1 = __shfl_xor(j1, off);
            float ov2 = __shfl_xor(v2, off);
            v2 = fminf(fminf(v2, ov2), fmaxf(v1, ov1));
            bool take = (ov1 < v1) || (ov1 == v1 && oj1 < j1);
            if (take) { v1 = ov1; j1 = oj1; }
        }
        if (ln31 == 0)
            redv[wv][wm * 32 + tt] = make_uint4(__float_as_uint(v1), (unsigned)j1,
                                                __float_as_uint(v2), 0u);
    }
    __syncthreads();
    double myv1 = 0.0;
    if (tid < 64) {
        int g = tid >> 5;   // token group
        uint4 a = redv[g * 4][tid];
        float v1 = __uint_as_float(a.x), v2 = __uint_as_float(a.z);
        int j1 = (int)a.y;
        #pragma unroll
        for (int w = 1; w < 4; ++w) {
            uint4 b = redv[g * 4 + w][tid];
            float wv1 = __uint_as_float(b.x), wv2 = __uint_as_float(b.z);
            v2 = fminf(fminf(v2, wv2), fmaxf(v1, wv1));
            bool take = (wv1 < v1) || (wv1 == v1 && (int)b.y < j1);
            if (take) { v1 = wv1; j1 = (int)b.y; }
        }
        idxs[tid] = j1;
        atomicAdd(&counts[j1], 1u);
        atomicAdd(&binc[docs[tid]], 1u);
        myv1 = (double)v1;
        if (v2 - v1 <= 2e-6f) {           // 8-sigma of fp16-path noise
            unsigned pq = atomicAdd(nflag, 1u);
            if (pq < FLAG_CAP) flag_list[pq] = (unsigned)(n0 + tid);
        }
    }
    dred[tid] = myv1;
    __syncthreads();

    // encodings: one-hot rows (nontemporal streaming output)
    for (int lin = tid; lin < 8192; lin += 512) {
        int t = lin >> 7, f4 = lin & 127;
        int idx = idxs[t];
        int b4 = f4 << 2;
        f32x4 v;
        v.x = (idx == b4)     ? 1.f : 0.f;
        v.y = (idx == b4 + 1) ? 1.f : 0.f;
        v.z = (idx == b4 + 2) ? 1.f : 0.f;
        v.w = (idx == b4 + 3) ? 1.f : 0.f;
        __builtin_nontemporal_store(v,
            (f32x4*)(out + OFF_ENC + ((size_t)(n0 + t) << 9) + (size_t)b4));
    }
    // quantized_words = codebook rows
    for (int lin = tid; lin < 8192; lin += 512) {
        int t = lin >> 7, f4 = lin & 127;
        f32x4 c4 = *(const f32x4*)(cw + (size_t)idxs[t] * DIM + (f4 << 2));
        __builtin_nontemporal_store(c4,
            (f32x4*)(out + OFF_QW + ((size_t)(n0 + t) << 9) + (size_t)(f4 << 2)));
    }
    // vq partial reduce (flagged tokens patched exactly by k_fixup)
    for (int st = 256; st; st >>= 1) {
        if (tid < st) dred[tid] += dred[tid + st];
        __syncthreads();
    }
    if (tid == 0) atomicAdd(vq_acc, dred[0]);
}

// ---------------------------------------------------------------------------
// Exact fp32 recompute for flagged near-tie tokens (vectorized, grid-stride).
__global__ __launch_bounds__(512)
void k_fixup(const int* __restrict__ doc, const float* __restrict__ emb,
             const float* __restrict__ cw, const float* __restrict__ n_arr,
             const unsigned* __restrict__ nflag, const unsigned* __restrict__ flag_list,
             float* __restrict__ out, unsigned* __restrict__ counts,
             double* __restrict__ vq_acc) {
    __shared__ float4 xs4[128];
    __shared__ double dr[128];
    __shared__ float nxf_sh;
    __shared__ int oldj_sh;
    __shared__ float vsh[512];
    __shared__ unsigned long long keys[512];

    const int tid = threadIdx.x;
    unsigned nf = *nflag;
    if (nf > FLAG_CAP) nf = FLAG_CAP;

    for (unsigned f = blockIdx.x; f < nf; f += gridDim.x) {
        int t = (int)flag_list[f];
        int dc = doc[t];
        if (tid < 128) {
            float4 v = *(const float4*)(emb + (size_t)dc * DIM + tid * 4);
            xs4[tid] = v;
            dr[tid] = (double)v.x*v.x + (double)v.y*v.y
                    + (double)v.z*v.z + (double)v.w*v.w;
        }
        if (tid == 0) oldj_sh = -1;
        __syncthreads();
        for (int st = 64; st; st >>= 1) {
            if (tid < st) dr[tid] += dr[tid + st];
            __syncthreads();
        }
        if (tid == 0) nxf_sh = (float)dr[0];
        {
            float e = out[OFF_ENC + (size_t)t * 512 + tid];
            if (e == 1.0f) oldj_sh = tid;
        }
        __syncthreads();
        {
            const float4* cr = (const float4*)(cw + (size_t)tid * DIM);
            float acc = 0.f;
            #pragma unroll 8
            for (int fq = 0; fq < 128; ++fq) {
                float4 c4 = cr[fq], x4 = xs4[fq];
                acc = fmaf(x4.x, c4.x, acc);
                acc = fmaf(x4.y, c4.y, acc);
                acc = fmaf(x4.z, c4.z, acc);
                acc = fmaf(x4.w, c4.w, acc);
            }
            float v = fmaf(-2.f, acc, nxf_sh + n_arr[tid]);
            vsh[tid] = v;
            keys[tid] = (((unsigned long long)__float_as_uint(v)) << 32) | (unsigned)tid;
        }
        __syncthreads();
        for (int st = 256; st; st >>= 1) {
            if (tid < st) {
                unsigned long long o = keys[tid + st];
                if (o < keys[tid]) keys[tid] = o;
            }
            __syncthreads();
        }
        int newj = (int)(keys[0] & 0xffffffffu);
        int oldj = oldj_sh;
        if (newj != oldj) {
            if (tid == 0) {
                out[OFF_ENC + (size_t)t * 512 + oldj] = 0.0f;
                out[OFF_ENC + (size_t)t * 512 + newj] = 1.0f;
                atomicSub(&counts[oldj], 1u);
                atomicAdd(&counts[newj], 1u);
                atomicAdd(vq_acc, (double)vsh[newj] - (double)vsh[oldj]);
            }
            if (tid < 128) {
                float4 x4 = xs4[tid];   // unused dummy read keeps xs4 live
                (void)x4;
                float4 cn = *(const float4*)(cw + (size_t)newj * DIM + tid * 4);
                *(float4*)&out[OFF_QW + (size_t)t * 512 + tid * 4] = cn;
            }
        } else if (tid < 64) {
            // patch vq: replace approx v1 with exact vsh[oldj]? approx kept
            // intentionally (error ~3e-7/token, negligible after mean).
        }
        __syncthreads();
    }
}

// ---------------------------------------------------------------------------
__global__ void k_docu(const unsigned* __restrict__ counts,
                       const float* __restrict__ cw, float* __restrict__ out_docu) {
    __shared__ float cnt[512];
    int tid = threadIdx.x;
    cnt[tid] = (float)counts[tid];
    __syncthreads();
    double a = 0.0;
    for (int j = 0; j < K_CON; ++j)
        a += (double)cnt[j] * (double)cw[(size_t)j * DIM + tid];
    out_docu[tid] = (float)(a * (1.0 / (double)N_TOK));
}

__global__ __launch_bounds__(256)
void k_lts(const float* __restrict__ cw, const float* __restrict__ n_arr,
           const float* __restrict__ s_arr, double* __restrict__ lts_acc) {
    __shared__ float ci[4 * 512];
    __shared__ float cjs[64 * 68];
    __shared__ double dred[256];
    const int tid = threadIdx.x;
    const int i0 = blockIdx.x * 4;
    #pragma unroll
    for (int rep = 0; rep < 2; ++rep) {
        int lin = rep * 256 + tid;
        int r = lin >> 7, fq = lin & 127;
        *(float4*)&ci[r*512 + fq*4] = *(const float4*)(cw + (size_t)(i0+r)*DIM + fq*4);
    }
    const int jj = tid & 63, ih = tid >> 6;
    const int ig = i0 + ih;
    const float ni = n_arr[ig], si = s_arr[ig];
    const float EPS = 1e-6f;
    double lsum = 0.0;
    for (int jc = 0; jc < 8; ++jc) {
        float accv = 0.f;
        for (int dc = 0; dc < 8; ++dc) {
            __syncthreads();
            #pragma unroll
            for (int rep = 0; rep < 4; ++rep) {
                int lin = rep * 256 + tid;
                int j = lin >> 4, fq = lin & 15;
                float4 v = *(const float4*)(cw + (size_t)(jc*64 + j)*DIM + dc*64 + fq*4);
                cjs[(fq*4+0)*68 + j] = v.x; cjs[(fq*4+1)*68 + j] = v.y;
                cjs[(fq*4+2)*68 + j] = v.z; cjs[(fq*4+3)*68 + j] = v.w;
            }
            __syncthreads();
            #pragma unroll 4
            for (int d = 0; d < 64; ++d)
                accv = fmaf(ci[ih*512 + dc*64 + d], cjs[d*68 + jj], accv);
        }
        int jg = jc*64 + jj;
        float ddv = ni + n_arr[jg] - 2.f*accv + 2.f*EPS*(si - s_arr[jg]) + 512.f*EPS*EPS;
        float dist = sqrtf(fmaxf(ddv, 0.f));
        lsum += (double)((ig == jg) ? dist : fmaxf(0.f, 1.f - dist));
    }
    dred[tid] = lsum;
    __syncthreads();
    for (int s = 128; s; s >>= 1) {
        if (tid < s) dred[tid] += dred[tid + s];
        __syncthreads();
    }
    if (tid == 0) atomicAdd(lts_acc, dred[0]);
}

// logits -> e = exp(logit + bias), per-block partial sums (no max: |logit| tiny)
__global__ void k_logexp(const float* __restrict__ docu, const float* __restrict__ q2w,
                         const float* __restrict__ q2b, float* __restrict__ evals,
                         double* __restrict__ parts) {
    __shared__ double esh[4];
    int wvi = threadIdx.x >> 6, lane = threadIdx.x & 63;
    int v = blockIdx.x * 4 + wvi;
    if (lane == 0) esh[wvi] = 0.0;
    if (v < VOCAB) {
        const float* wr = q2w + (size_t)v * DIM;
        float4 a = *(const float4*)(wr + lane*8);
        float4 b = *(const float4*)(wr + lane*8 + 4);
        float4 da = *(const float4*)(docu + lane*8);
        float4 db = *(const float4*)(docu + lane*8 + 4);
        float p = a.x*da.x + a.y*da.y + a.z*da.z + a.w*da.w
                + b.x*db.x + b.y*db.y + b.z*db.z + b.w*db.w;
        for (int off = 32; off; off >>= 1) p += __shfl_down(p, off);
        if (lane == 0) {
            float e = expf(p + q2b[v]);
            evals[v] = e;
            esh[wvi] = (double)e;
        }
    }
    __syncthreads();
    if (threadIdx.x == 0)
        parts[blockIdx.x] = esh[0] + esh[1] + esh[2] + esh[3];
}

__global__ void k_sumred(const double* __restrict__ parts, double* __restrict__ sumv) {
    __shared__ double red[256];
    int tid = threadIdx.x;
    double s = 0.0;
    for (int i = tid; i < NPARTS; i += 256) s += parts[i];
    red[tid] = s; __syncthreads();
    for (int st = 128; st; st >>= 1) {
        if (tid < st) red[tid] += red[tid + st];
        __syncthreads();
    }
    if (tid == 0) *sumv = red[0];
}

__global__ void k_final(const float* __restrict__ evals,
                        const double* __restrict__ sumv, const unsigned* __restrict__ binc,
                        const double* __restrict__ vq_acc, const double* __restrict__ lts_acc,
                        float* __restrict__ out) {
    int v = blockIdx.x * 256 + threadIdx.x;
    if (v < VOCAB) {
        float s = (float)(*sumv);
        float p = evals[v] / s;
        out[OFF_OUT + v] = logf(p + 1e-6f) * (float)binc[v];
    }
    if (v == 0) {
        out[OFF_VQ]  = (float)(1.25 * (*vq_acc) * (1.0 / 67108864.0));
        out[OFF_LTS] = (float)((*lts_acc) * (1.0 / 262144.0));
    }
}

// ---------------------------------------------------------------------------
extern "C" void kernel_launch(void* const* d_in, const int* in_sizes, int n_in,
                              void* d_out, int out_size, void* d_ws, size_t ws_size,
                              hipStream_t stream) {
    const int*   doc = (const int*)d_in[0];
    const float* emb = (const float*)d_in[1];
    const float* cw  = (const float*)d_in[2];
    const float* q2w = (const float*)d_in[3];
    const float* q2b = (const float*)d_in[4];
    float* out = (float*)d_out;
    char* ws = (char*)d_ws;

    unsigned* counts = (unsigned*)(ws + WS_COUNTS);
    double*   vq_acc = (double*)(ws + WS_VQ);
    double*   lts_acc= (double*)(ws + WS_LTS);
    double*   sumv   = (double*)(ws + WS_SUMV);
    unsigned* nflag  = (unsigned*)(ws + WS_NFLAG);
    float*    n_arr  = (float*)(ws + WS_NARR);
    float*    s_arr  = (float*)(ws + WS_SARR);
    unsigned* binc   = (unsigned*)(ws + WS_BINC);
    float*    evals  = (float*)(ws + WS_LOGITS);
    unsigned* flags  = (unsigned*)(ws + WS_FLAGS);
    double*   parts  = (double*)(ws + WS_PART);

    _Float16* b1;
    hipGetSymbolAddress((void**)&b1, HIP_SYMBOL(g_B1));

    hipMemsetAsync(ws, 0, 4096, stream);
    hipMemsetAsync(binc, 0, VOCAB * sizeof(unsigned), stream);

    hipLaunchKernelGGL(k_nsprep, dim3(128),  dim3(256), 0, stream, cw, n_arr, s_arr, b1);
    hipLaunchKernelGGL(k_main,   dim3(2048), dim3(512), 0, stream, doc, emb, cw, n_arr,
                       out, counts, binc, vq_acc, nflag, flags);
    hipLaunchKernelGGL(k_fixup,  dim3(2048), dim3(512), 0, stream, doc, emb, cw, n_arr,
                       nflag, flags, out, counts, vq_acc);
    hipLaunchKernelGGL(k_docu,   dim3(1),    dim3(512), 0, stream, counts, cw, out + OFF_DOCU);
    hipLaunchKernelGGL(k_lts,    dim3(128),  dim3(256), 0, stream, cw, n_arr, s_arr, lts_acc);
    hipLaunchKernelGGL(k_logexp, dim3(NPARTS), dim3(256), 0, stream,
                       out + OFF_DOCU, q2w, q2b, evals, parts);
    hipLaunchKernelGGL(k_sumred, dim3(1), dim3(256), 0, stream, parts, sumv);
    hipLaunchKernelGGL(k_final,  dim3((VOCAB + 255) / 256), dim3(256), 0, stream,
                       evals, sumv, binc, vq_acc, lts_acc, out);
}

// Round 9
// 512.827 us; speedup vs baseline: 1.9037x; 1.6808x over previous
//
#include <hip/hip_runtime.h>
#include <math.h>

#define N_TOK 131072
#define VOCAB 50257
#define DIM   512
#define K_CON 512
#define NPARTS 12565   // ceil(VOCAB/4)

// d_out layout (float32 elements)
#define OFF_ENC  ((size_t)0)
#define OFF_QW   ((size_t)67108864)
#define OFF_DOCU ((size_t)134217728)
#define OFF_OUT  ((size_t)134218240)
#define OFF_VQ   ((size_t)134268497)
#define OFF_LTS  ((size_t)134268498)

// ws layout (bytes)
#define WS_COUNTS 0        // 512 * u32
#define WS_VQ     2048     // double
#define WS_LTS    2056     // double
#define WS_SUMV   2072     // double
#define WS_NFLAG  2080     // u32
#define WS_NARR   4096     // 512 f32
#define WS_SARR   6144     // 512 f32
#define WS_BINC   8192     // VOCAB u32
#define WS_LOGITS 209920   // VOCAB f32 (holds exp(logit))
#define WS_FLAGS  411648   // FLAG_CAP u32  (ends 542720)
#define WS_PART   544768   // NPARTS double (ends 645288)
#define FLAG_CAP  32768

typedef __attribute__((ext_vector_type(4)))  float f32x4;
typedef __attribute__((ext_vector_type(8)))  _Float16 f16x8;
typedef __attribute__((ext_vector_type(16))) float f32x16;

// Codebook as fp16 of (512*c), MFMA fragment layout:
// per step s (16 fp32 dims): [hv 0..1][concept 0..511] x f16x8
//   hv selects dims s*16+hv*8..+7.  Phase = 2 steps = 32 KB.
__device__ _Float16 g_B1[32 * 2 * 512 * 8];   // 512 KB, L2-resident

__device__ inline void gload16(const void* g, void* l) {
    __builtin_amdgcn_global_load_lds(
        (const __attribute__((address_space(1))) unsigned int*)g,
        (__attribute__((address_space(3))) unsigned int*)l, 16, 0, 0);
}

__device__ __forceinline__ f16x8 cvt8(const float4 a0, const float4 a1) {
    f16x8 h;
    h[0] = (_Float16)a0.x; h[1] = (_Float16)a0.y;
    h[2] = (_Float16)a0.z; h[3] = (_Float16)a0.w;
    h[4] = (_Float16)a1.x; h[5] = (_Float16)a1.y;
    h[6] = (_Float16)a1.z; h[7] = (_Float16)a1.w;
    return h;
}

// ---------------------------------------------------------------------------
// merged: n/s arrays + codebook fp16 (512*c) prep
__global__ void k_nsprep(const float* __restrict__ cw, float* __restrict__ n_arr,
                         float* __restrict__ s_arr, _Float16* __restrict__ b1) {
    int w = threadIdx.x >> 6, lane = threadIdx.x & 63;
    int r = blockIdx.x * 4 + w;
    const float* row = cw + (size_t)r * DIM;
    {
        float4 a = *(const float4*)(row + lane * 8);
        float4 b = *(const float4*)(row + lane * 8 + 4);
        float v[8] = {a.x,a.y,a.z,a.w,b.x,b.y,b.z,b.w};
        double na = 0.0, sa = 0.0;
        #pragma unroll
        for (int e = 0; e < 8; ++e) { na += (double)v[e]*v[e]; sa += (double)v[e]; }
        for (int off = 32; off; off >>= 1) {
            na += __shfl_down(na, off);
            sa += __shfl_down(sa, off);
        }
        if (lane == 0) { n_arr[r] = (float)na; s_arr[r] = (float)sa; }
    }
    {
        int s = lane >> 1, hf = lane & 1;
        const float* p = row + s * 16 + hf * 8;
        float4 xa = *(const float4*)p;
        float4 xb = *(const float4*)(p + 4);
        float xf[8] = {xa.x,xa.y,xa.z,xa.w,xb.x,xb.y,xb.z,xb.w};
        f16x8 h8;
        #pragma unroll
        for (int e = 0; e < 8; ++e) h8[e] = (_Float16)(xf[e] * 512.0f);
        *(f16x8*)&b1[(((size_t)s * 2 + hf) * 512 + r) * 8] = h8;
    }
}

// ---------------------------------------------------------------------------
// Main: fp16 single-term MFMA distance GEMM (S = x_h . (512 c)_h; d =
// fmaf(-2^-8, S, nx+nc)). 512 threads = 8 waves (2 token-groups x 4
// concept-quarters). B in 64 KB LDS double-buffer, 16 sync-phases (BK=32).
// ARCH-VGPR BUDGET NOTE: acc[4] (64 AGPRs) leaves only ~64 arch VGPRs at
// this occupancy — A prefetch must stay at 1 phase (4x float4). Round 8's
// 2-phase prefetch spilled (WRITE_SIZE 1.75 GB).
__global__ __launch_bounds__(512, 4)
void k_main(const int* __restrict__ doc, const float* __restrict__ emb,
            const float* __restrict__ cw, const float* __restrict__ n_arr,
            float* __restrict__ out, unsigned* __restrict__ counts,
            unsigned* __restrict__ binc,
            double* __restrict__ vq_acc, unsigned* __restrict__ nflag,
            unsigned* __restrict__ flag_list) {
    __shared__ f16x8 bsh[2][2048];      // 2 x 32 KB double-buffered phase tile
    __shared__ float nsl[512];
    __shared__ float nxs[64];
    __shared__ uint4 redv[8][64];       // 8 KB
    __shared__ int docs[64];
    __shared__ int idxs[64];
    __shared__ double dred[512];        // 4 KB

    const int tid   = threadIdx.x;
    const int n0    = blockIdx.x * 64;
    const int lane  = tid & 63;
    const int wv    = tid >> 6;
    const int wm    = wv >> 2;          // token group 0/1
    const int wq    = wv & 3;           // concept quarter
    const int hv    = lane >> 5;
    const int ln31  = lane & 31;
    const int cbase = wq * 128 + ln31;

    if (tid < 64) docs[tid] = doc[n0 + tid];
    nsl[tid] = n_arr[tid];
    __syncthreads();

#define STAGE_PHASE(P, DST)                                                   \
    {                                                                         \
        const char* srcb = (const char*)g_B1 + (size_t)(P) * 32768;           \
        char* dstb = (char*)(DST);                                            \
        _Pragma("unroll")                                                     \
        for (int i = 0; i < 4; ++i)                                           \
            gload16(srcb + i * 8192 + tid * 16, dstb + i * 8192 + tid * 16);  \
    }

    // stage phase 0 into buf 0 (drained by the pre-pass barrier)
    STAGE_PHASE(0, bsh[0]);

    // nx pre-pass: 8 threads per token, double partials (also warms L2)
    {
        int t = tid >> 3, q = tid & 7;
        const float* xr = emb + (size_t)docs[t] * DIM + q * 64;
        double px = 0.0;
        for (int f = 0; f < 16; ++f) {
            float4 v = *(const float4*)(xr + f * 4);
            px += (double)v.x*v.x + (double)v.y*v.y + (double)v.z*v.z + (double)v.w*v.w;
        }
        dred[tid] = px;
    }

    const float* xrow = emb + (size_t)docs[wm * 32 + ln31] * DIM;
    // prefetch A phase 0: dims {hv*8..+7, 16+hv*8..+7}
    float4 a0 = *(const float4*)(xrow + hv * 8);
    float4 a1 = *(const float4*)(xrow + hv * 8 + 4);
    float4 a2 = *(const float4*)(xrow + 16 + hv * 8);
    float4 a3 = *(const float4*)(xrow + 16 + hv * 8 + 4);

    __syncthreads();   // drains staging 0 + A + nx loads
    if (tid < 64) {
        double s = 0.0;
        #pragma unroll
        for (int q = 0; q < 8; ++q) s += dred[tid * 8 + q];
        nxs[tid] = (float)s;
    }

    f32x16 acc[4];
    #pragma unroll
    for (int n = 0; n < 4; ++n) acc[n] = (f32x16)(0.0f);

    #pragma unroll 2
    for (int p = 0; p < 16; ++p) {
        const int cur = p & 1;
        // issue next-phase staging FIRST: full compute phase to complete
        if (p < 15) STAGE_PHASE(p + 1, bsh[cur ^ 1]);
        // convert prefetched A (both sub-steps)
        f16x8 x0 = cvt8(a0, a1);
        f16x8 x1 = cvt8(a2, a3);
        // prefetch next phase A
        if (p < 15) {
            const float* px = xrow + (p + 1) * 32 + hv * 8;
            a0 = *(const float4*)px;
            a1 = *(const float4*)(px + 4);
            a2 = *(const float4*)(px + 16);
            a3 = *(const float4*)(px + 20);
        }
        // MFMA on current buffer: sub 0 then sub 1
        const f16x8* bb = bsh[cur];
        #pragma unroll
        for (int n = 0; n < 4; ++n) {
            f16x8 b0 = bb[hv * 512 + cbase + n * 32];
            acc[n] = __builtin_amdgcn_mfma_f32_32x32x16_f16(x0, b0, acc[n], 0, 0, 0);
        }
        #pragma unroll
        for (int n = 0; n < 4; ++n) {
            f16x8 b1 = bb[1024 + hv * 512 + cbase + n * 32];
            acc[n] = __builtin_amdgcn_mfma_f32_32x32x16_f16(x1, b1, acc[n], 0, 0, 0);
        }
        __syncthreads();   // drains staging vmcnt; buf cur reads complete
    }
#undef STAGE_PHASE

    float nsv[4];
    #pragma unroll
    for (int n = 0; n < 4; ++n) nsv[n] = nsl[cbase + n * 32];

    // per-row argmin + second best; C/D: col=lane&31, row=(r&3)+8*(r>>2)+4*hv
    // acc holds S = x_h . (512 c)_h ; d = fl(t1 - 2*(S/512)) = fmaf(-2^-8,S,t1)
    #pragma unroll
    for (int r = 0; r < 16; ++r) {
        int tt = (r & 3) + ((r >> 2) << 3) + (hv << 2);   // 0..31 within wm
        float nxr = nxs[wm * 32 + tt];
        float v1 = INFINITY, v2 = INFINITY; int j1 = 0x7fffffff;
        #pragma unroll
        for (int n = 0; n < 4; ++n) {
            float d = fmaf(-0.00390625f, acc[n][r], nxr + nsv[n]);
            int jj = cbase + n * 32;
            if (d < v1) { v2 = v1; v1 = d; j1 = jj; }
            else if (d < v2) { v2 = d; }
        }
        #pragma unroll
        for (int off = 1; off < 32; off <<= 1) {
            float ov1 = __shfl_xor(v1, off);
            int   oj1 = __shfl_xor(j1, off);
            float ov2 = __shfl_xor(v2, off);
            v2 = fminf(fminf(v2, ov2), fmaxf(v1, ov1));
            bool take = (ov1 < v1) || (ov1 == v1 && oj1 < j1);
            if (take) { v1 = ov1; j1 = oj1; }
        }
        if (ln31 == 0)
            redv[wv][wm * 32 + tt] = make_uint4(__float_as_uint(v1), (unsigned)j1,
                                                __float_as_uint(v2), 0u);
    }
    __syncthreads();
    double myv1 = 0.0;
    if (tid < 64) {
        int g = tid >> 5;   // token group
        uint4 a = redv[g * 4][tid];
        float v1 = __uint_as_float(a.x), v2 = __uint_as_float(a.z);
        int j1 = (int)a.y;
        #pragma unroll
        for (int w = 1; w < 4; ++w) {
            uint4 b = redv[g * 4 + w][tid];
            float wv1 = __uint_as_float(b.x), wv2 = __uint_as_float(b.z);
            v2 = fminf(fminf(v2, wv2), fmaxf(v1, wv1));
            bool take = (wv1 < v1) || (wv1 == v1 && (int)b.y < j1);
            if (take) { v1 = wv1; j1 = (int)b.y; }
        }
        idxs[tid] = j1;
        atomicAdd(&counts[j1], 1u);
        atomicAdd(&binc[docs[tid]], 1u);
        myv1 = (double)v1;
        if (v2 - v1 <= 2e-6f) {           // ~8 sigma of fp16-path noise
            unsigned pq = atomicAdd(nflag, 1u);
            if (pq < FLAG_CAP) flag_list[pq] = (unsigned)(n0 + tid);
        }
    }
    dred[tid] = myv1;
    __syncthreads();

    // encodings: one-hot rows (nontemporal streaming output)
    for (int lin = tid; lin < 8192; lin += 512) {
        int t = lin >> 7, f4 = lin & 127;
        int idx = idxs[t];
        int b4 = f4 << 2;
        f32x4 v;
        v.x = (idx == b4)     ? 1.f : 0.f;
        v.y = (idx == b4 + 1) ? 1.f : 0.f;
        v.z = (idx == b4 + 2) ? 1.f : 0.f;
        v.w = (idx == b4 + 3) ? 1.f : 0.f;
        __builtin_nontemporal_store(v,
            (f32x4*)(out + OFF_ENC + ((size_t)(n0 + t) << 9) + (size_t)b4));
    }
    // quantized_words = codebook rows
    for (int lin = tid; lin < 8192; lin += 512) {
        int t = lin >> 7, f4 = lin & 127;
        f32x4 c4 = *(const f32x4*)(cw + (size_t)idxs[t] * DIM + (f4 << 2));
        __builtin_nontemporal_store(c4,
            (f32x4*)(out + OFF_QW + ((size_t)(n0 + t) << 9) + (size_t)(f4 << 2)));
    }
    // vq partial reduce (flagged tokens patched exactly by k_fixup)
    for (int st = 256; st; st >>= 1) {
        if (tid < st) dred[tid] += dred[tid + st];
        __syncthreads();
    }
    if (tid == 0) atomicAdd(vq_acc, dred[0]);
}

// ---------------------------------------------------------------------------
// Exact fp32 recompute for flagged near-tie tokens (vectorized, grid-stride).
__global__ __launch_bounds__(512)
void k_fixup(const int* __restrict__ doc, const float* __restrict__ emb,
             const float* __restrict__ cw, const float* __restrict__ n_arr,
             const unsigned* __restrict__ nflag, const unsigned* __restrict__ flag_list,
             float* __restrict__ out, unsigned* __restrict__ counts,
             double* __restrict__ vq_acc) {
    __shared__ float4 xs4[128];
    __shared__ double dr[128];
    __shared__ float nxf_sh;
    __shared__ int oldj_sh;
    __shared__ float vsh[512];
    __shared__ unsigned long long keys[512];

    const int tid = threadIdx.x;
    unsigned nf = *nflag;
    if (nf > FLAG_CAP) nf = FLAG_CAP;

    for (unsigned f = blockIdx.x; f < nf; f += gridDim.x) {
        int t = (int)flag_list[f];
        int dc = doc[t];
        if (tid < 128) {
            float4 v = *(const float4*)(emb + (size_t)dc * DIM + tid * 4);
            xs4[tid] = v;
            dr[tid] = (double)v.x*v.x + (double)v.y*v.y
                    + (double)v.z*v.z + (double)v.w*v.w;
        }
        if (tid == 0) oldj_sh = -1;
        __syncthreads();
        for (int st = 64; st; st >>= 1) {
            if (tid < st) dr[tid] += dr[tid + st];
            __syncthreads();
        }
        if (tid == 0) nxf_sh = (float)dr[0];
        {
            float e = out[OFF_ENC + (size_t)t * 512 + tid];
            if (e == 1.0f) oldj_sh = tid;
        }
        __syncthreads();
        {
            const float4* cr = (const float4*)(cw + (size_t)tid * DIM);
            float acc = 0.f;
            #pragma unroll 8
            for (int fq = 0; fq < 128; ++fq) {
                float4 c4 = cr[fq], x4 = xs4[fq];
                acc = fmaf(x4.x, c4.x, acc);
                acc = fmaf(x4.y, c4.y, acc);
                acc = fmaf(x4.z, c4.z, acc);
                acc = fmaf(x4.w, c4.w, acc);
            }
            float v = fmaf(-2.f, acc, nxf_sh + n_arr[tid]);
            vsh[tid] = v;
            keys[tid] = (((unsigned long long)__float_as_uint(v)) << 32) | (unsigned)tid;
        }
        __syncthreads();
        for (int st = 256; st; st >>= 1) {
            if (tid < st) {
                unsigned long long o = keys[tid + st];
                if (o < keys[tid]) keys[tid] = o;
            }
            __syncthreads();
        }
        int newj = (int)(keys[0] & 0xffffffffu);
        int oldj = oldj_sh;
        if (newj != oldj) {
            if (tid == 0) {
                out[OFF_ENC + (size_t)t * 512 + oldj] = 0.0f;
                out[OFF_ENC + (size_t)t * 512 + newj] = 1.0f;
                atomicSub(&counts[oldj], 1u);
                atomicAdd(&counts[newj], 1u);
                atomicAdd(vq_acc, (double)vsh[newj] - (double)vsh[oldj]);
            }
            if (tid < 128) {
                float4 cn = *(const float4*)(cw + (size_t)newj * DIM + tid * 4);
                *(float4*)&out[OFF_QW + (size_t)t * 512 + tid * 4] = cn;
            }
        }
        __syncthreads();
    }
}

// ---------------------------------------------------------------------------
__global__ void k_docu(const unsigned* __restrict__ counts,
                       const float* __restrict__ cw, float* __restrict__ out_docu) {
    __shared__ float cnt[512];
    int tid = threadIdx.x;
    cnt[tid] = (float)counts[tid];
    __syncthreads();
    double a = 0.0;
    for (int j = 0; j < K_CON; ++j)
        a += (double)cnt[j] * (double)cw[(size_t)j * DIM + tid];
    out_docu[tid] = (float)(a * (1.0 / (double)N_TOK));
}

__global__ __launch_bounds__(256)
void k_lts(const float* __restrict__ cw, const float* __restrict__ n_arr,
           const float* __restrict__ s_arr, double* __restrict__ lts_acc) {
    __shared__ float ci[4 * 512];
    __shared__ float cjs[64 * 68];
    __shared__ double dred[256];
    const int tid = threadIdx.x;
    const int i0 = blockIdx.x * 4;
    #pragma unroll
    for (int rep = 0; rep < 2; ++rep) {
        int lin = rep * 256 + tid;
        int r = lin >> 7, fq = lin & 127;
        *(float4*)&ci[r*512 + fq*4] = *(const float4*)(cw + (size_t)(i0+r)*DIM + fq*4);
    }
    const int jj = tid & 63, ih = tid >> 6;
    const int ig = i0 + ih;
    const float ni = n_arr[ig], si = s_arr[ig];
    const float EPS = 1e-6f;
    double lsum = 0.0;
    for (int jc = 0; jc < 8; ++jc) {
        float accv = 0.f;
        for (int dc = 0; dc < 8; ++dc) {
            __syncthreads();
            #pragma unroll
            for (int rep = 0; rep < 4; ++rep) {
                int lin = rep * 256 + tid;
                int j = lin >> 4, fq = lin & 15;
                float4 v = *(const float4*)(cw + (size_t)(jc*64 + j)*DIM + dc*64 + fq*4);
                cjs[(fq*4+0)*68 + j] = v.x; cjs[(fq*4+1)*68 + j] = v.y;
                cjs[(fq*4+2)*68 + j] = v.z; cjs[(fq*4+3)*68 + j] = v.w;
            }
            __syncthreads();
            #pragma unroll 4
            for (int d = 0; d < 64; ++d)
                accv = fmaf(ci[ih*512 + dc*64 + d], cjs[d*68 + jj], accv);
        }
        int jg = jc*64 + jj;
        float ddv = ni + n_arr[jg] - 2.f*accv + 2.f*EPS*(si - s_arr[jg]) + 512.f*EPS*EPS;
        float dist = sqrtf(fmaxf(ddv, 0.f));
        lsum += (double)((ig == jg) ? dist : fmaxf(0.f, 1.f - dist));
    }
    dred[tid] = lsum;
    __syncthreads();
    for (int s = 128; s; s >>= 1) {
        if (tid < s) dred[tid] += dred[tid + s];
        __syncthreads();
    }
    if (tid == 0) atomicAdd(lts_acc, dred[0]);
}

// logits -> e = exp(logit + bias), per-block partial sums (no max: |logit| tiny)
__global__ void k_logexp(const float* __restrict__ docu, const float* __restrict__ q2w,
                         const float* __restrict__ q2b, float* __restrict__ evals,
                         double* __restrict__ parts) {
    __shared__ double esh[4];
    int wvi = threadIdx.x >> 6, lane = threadIdx.x & 63;
    int v = blockIdx.x * 4 + wvi;
    if (lane == 0) esh[wvi] = 0.0;
    if (v < VOCAB) {
        const float* wr = q2w + (size_t)v * DIM;
        float4 a = *(const float4*)(wr + lane*8);
        float4 b = *(const float4*)(wr + lane*8 + 4);
        float4 da = *(const float4*)(docu + lane*8);
        float4 db = *(const float4*)(docu + lane*8 + 4);
        float p = a.x*da.x + a.y*da.y + a.z*da.z + a.w*da.w
                + b.x*db.x + b.y*db.y + b.z*db.z + b.w*db.w;
        for (int off = 32; off; off >>= 1) p += __shfl_down(p, off);
        if (lane == 0) {
            float e = expf(p + q2b[v]);
            evals[v] = e;
            esh[wvi] = (double)e;
        }
    }
    __syncthreads();
    if (threadIdx.x == 0)
        parts[blockIdx.x] = esh[0] + esh[1] + esh[2] + esh[3];
}

__global__ void k_sumred(const double* __restrict__ parts, double* __restrict__ sumv) {
    __shared__ double red[256];
    int tid = threadIdx.x;
    double s = 0.0;
    for (int i = tid; i < NPARTS; i += 256) s += parts[i];
    red[tid] = s; __syncthreads();
    for (int st = 128; st; st >>= 1) {
        if (tid < st) red[tid] += red[tid + st];
        __syncthreads();
    }
    if (tid == 0) *sumv = red[0];
}

__global__ void k_final(const float* __restrict__ evals,
                        const double* __restrict__ sumv, const unsigned* __restrict__ binc,
                        const double* __restrict__ vq_acc, const double* __restrict__ lts_acc,
                        float* __restrict__ out) {
    int v = blockIdx.x * 256 + threadIdx.x;
    if (v < VOCAB) {
        float s = (float)(*sumv);
        float p = evals[v] / s;
        out[OFF_OUT + v] = logf(p + 1e-6f) * (float)binc[v];
    }
    if (v == 0) {
        out[OFF_VQ]  = (float)(1.25 * (*vq_acc) * (1.0 / 67108864.0));
        out[OFF_LTS] = (float)((*lts_acc) * (1.0 / 262144.0));
    }
}

// ---------------------------------------------------------------------------
extern "C" void kernel_launch(void* const* d_in, const int* in_sizes, int n_in,
                              void* d_out, int out_size, void* d_ws, size_t ws_size,
                              hipStream_t stream) {
    const int*   doc = (const int*)d_in[0];
    const float* emb = (const float*)d_in[1];
    const float* cw  = (const float*)d_in[2];
    const float* q2w = (const float*)d_in[3];
    const float* q2b = (const float*)d_in[4];
    float* out = (float*)d_out;
    char* ws = (char*)d_ws;

    unsigned* counts = (unsigned*)(ws + WS_COUNTS);
    double*   vq_acc = (double*)(ws + WS_VQ);
    double*   lts_acc= (double*)(ws + WS_LTS);
    double*   sumv   = (double*)(ws + WS_SUMV);
    unsigned* nflag  = (unsigned*)(ws + WS_NFLAG);
    float*    n_arr  = (float*)(ws + WS_NARR);
    float*    s_arr  = (float*)(ws + WS_SARR);
    unsigned* binc   = (unsigned*)(ws + WS_BINC);
    float*    evals  = (float*)(ws + WS_LOGITS);
    unsigned* flags  = (unsigned*)(ws + WS_FLAGS);
    double*   parts  = (double*)(ws + WS_PART);

    _Float16* b1;
    hipGetSymbolAddress((void**)&b1, HIP_SYMBOL(g_B1));

    hipMemsetAsync(ws, 0, 4096, stream);
    hipMemsetAsync(binc, 0, VOCAB * sizeof(unsigned), stream);

    hipLaunchKernelGGL(k_nsprep, dim3(128),  dim3(256), 0, stream, cw, n_arr, s_arr, b1);
    hipLaunchKernelGGL(k_main,   dim3(2048), dim3(512), 0, stream, doc, emb, cw, n_arr,
                       out, counts, binc, vq_acc, nflag, flags);
    hipLaunchKernelGGL(k_fixup,  dim3(2048), dim3(512), 0, stream, doc, emb, cw, n_arr,
                       nflag, flags, out, counts, vq_acc);
    hipLaunchKernelGGL(k_docu,   dim3(1),    dim3(512), 0, stream, counts, cw, out + OFF_DOCU);
    hipLaunchKernelGGL(k_lts,    dim3(128),  dim3(256), 0, stream, cw, n_arr, s_arr, lts_acc);
    hipLaunchKernelGGL(k_logexp, dim3(NPARTS), dim3(256), 0, stream,
                       out + OFF_DOCU, q2w, q2b, evals, parts);
    hipLaunchKernelGGL(k_sumred, dim3(1), dim3(256), 0, stream, parts, sumv);
    hipLaunchKernelGGL(k_final,  dim3((VOCAB + 255) / 256), dim3(256), 0, stream,
                       evals, sumv, binc, vq_acc, lts_acc, out);
}